// Round 9
// baseline (427.482 us; speedup 1.0000x reference)
//
#include <hip/hip_runtime.h>

// Capsule dynamic routing — R8 lane map + n-split waves for 2x wave supply.
// u_i:(B,N,DI) f32, w:(1,N,NO,DI,DE) f32, bias:(N,NO,1) f32, r=3.
// Identity: logits_r = u_ji . vsum (vsum = running sum of v; u_ji includes
// bias so the bias term folds in automatically).
// Lane map (unchanged from R8): eq = lane&3 (e-quad), bb = lane>>2 (16 b/wave).
// NEW: the 4 waves of a block share the SAME 16 b and split the 16-n tile
// (4 n each); partial acc combined via 10 KB LDS float atomics (epilogue only,
// 4-way contention). Grid 72x16 = 1152 blocks x 4 waves = 18 waves/CU.
// s_part halves to 11.8 MB -> squash traffic halves.

#define B    256
#define N    1152
#define NO   10
#define DI   8
#define DE   16
#define NTILE   16
#define NTILES  72     // N / NTILE
#define NPW     4      // n per wave
#define THREADS 256    // 4 waves
#define BGS     16     // b-groups (16 b each)

// ws layout (floats) — 11.96 MB
#define SP_OFF 0
#define SP_SZ  (NTILES * B * NO * DE)   // 2,949,120
#define VS_OFF (SP_OFF + SP_SZ)
#define VS_SZ  (B * NO * DE)            // 40,960

// ---------------------------------------------------------------------------
// Routing pass. Grid: (72 n-tiles, 16 b-groups) x 256 threads.
// ---------------------------------------------------------------------------
__global__ __launch_bounds__(THREADS, 3)
void routing_kernel(const float* __restrict__ u,
                    const float* __restrict__ w,
                    const float* __restrict__ bias,
                    const float* __restrict__ vsum,
                    float* __restrict__ s_part,
                    const int has_v) {
    __shared__ float sacc[16 * NO * DE];   // 10 KB block accumulator
    const int tid  = threadIdx.x;
    const int lane = tid & 63;
    const int eq   = lane & 3;        // e-quad: e = eq*4..eq*4+3
    const int bb   = lane >> 2;       // 0..15
    const int wv   = tid >> 6;        // wave id -> n quarter
    const int b    = blockIdx.y * 16 + bb;
    const int n0   = blockIdx.x * NTILE + wv * NPW;

    // zero the block accumulator (barrier is after the compute loop)
    for (int i = tid; i < 16 * NO * DE; i += THREADS) sacc[i] = 0.f;

    // vsum fragments (loop-invariant): vv[o] = vsum[b][o][eq*4..+3]
    float4 vv[NO];
#pragma unroll
    for (int o = 0; o < NO; ++o) vv[o] = make_float4(0.f, 0.f, 0.f, 0.f);
    if (has_v) {
#pragma unroll
        for (int o = 0; o < NO; ++o)
            vv[o] = *(const float4*)(vsum + ((size_t)b * NO + o) * DE + eq * 4);
    }

    float4 acc[NO];
#pragma unroll
    for (int o = 0; o < NO; ++o) acc[o] = make_float4(0.f, 0.f, 0.f, 0.f);

    for (int i = 0; i < NPW; ++i) {
        const int n = n0 + i;

        // u row for this b (4 eq-lanes share addr -> 16 unique 32B segs/wave)
        const float* up = u + ((size_t)b * N + n) * DI;
        const float4 u0 = *(const float4*)up;
        const float4 u1 = *(const float4*)(up + 4);
        const float ur[DI] = {u0.x, u0.y, u0.z, u0.w, u1.x, u1.y, u1.z, u1.w};

        // u_ji for all 10 o at this thread's e-quad.
        // w addr varies only with eq across the wave -> one 64B line per load.
        const float* wp = w + (size_t)n * (NO * DI * DE) + eq * 4;
        float4 uji[NO];
#pragma unroll
        for (int o = 0; o < NO; ++o) {
            const float bv = bias[n * NO + o];
            float4 a = make_float4(bv, bv, bv, bv);
            const float* wo = wp + o * (DI * DE);
#pragma unroll
            for (int d = 0; d < DI; ++d) {
                const float4 w4 = *(const float4*)(wo + d * DE);
                a.x += ur[d] * w4.x; a.y += ur[d] * w4.y;
                a.z += ur[d] * w4.z; a.w += ur[d] * w4.w;
            }
            uji[o] = a;
        }

        float c[NO];
        if (has_v) {
            // logits: partial dot over this eq, reduced across the eq quad
            float l[NO];
#pragma unroll
            for (int o = 0; o < NO; ++o) {
                float dt = uji[o].x * vv[o].x + uji[o].y * vv[o].y
                         + uji[o].z * vv[o].z + uji[o].w * vv[o].w;
                dt += __shfl_xor(dt, 1);
                dt += __shfl_xor(dt, 2);     // full 16-e dot, all eq lanes
                l[o] = dt;
            }
            // softmax over o — fully in-register
            float m = l[0];
#pragma unroll
            for (int o = 1; o < NO; ++o) m = fmaxf(m, l[o]);
            float sum = 0.f;
#pragma unroll
            for (int o = 0; o < NO; ++o) { c[o] = __expf(l[o] - m); sum += c[o]; }
            const float inv = 1.f / sum;
#pragma unroll
            for (int o = 0; o < NO; ++o) c[o] *= inv;
        } else {
#pragma unroll
            for (int o = 0; o < NO; ++o) c[o] = 0.1f;   // softmax of zeros
        }

#pragma unroll
        for (int o = 0; o < NO; ++o) {
            acc[o].x += c[o] * uji[o].x; acc[o].y += c[o] * uji[o].y;
            acc[o].z += c[o] * uji[o].z; acc[o].w += c[o] * uji[o].w;
        }
    }

    // combine the 4 waves' partials: LDS float atomics (4-way contention max)
    __syncthreads();                        // zero-init visible to all
    float* sb = sacc + (bb * NO) * DE + eq * 4;
#pragma unroll
    for (int o = 0; o < NO; ++o) {
        atomicAdd(sb + o * DE + 0, acc[o].x);
        atomicAdd(sb + o * DE + 1, acc[o].y);
        atomicAdd(sb + o * DE + 2, acc[o].z);
        atomicAdd(sb + o * DE + 3, acc[o].w);
    }
    __syncthreads();

    // write out: s_part[tile][b][o][e]; sacc bands (160 floats/bb) match layout
    const size_t base = ((size_t)blockIdx.x * B + blockIdx.y * 16) * (NO * DE);
    for (int l4 = tid; l4 < (16 * NO * DE) / 4; l4 += THREADS) {
        const float4 val = ((const float4*)sacc)[l4];
        *(float4*)(s_part + base + (size_t)l4 * 4) = val;
    }
}

// ---------------------------------------------------------------------------
// Squash: s = sum_tiles s_part; v = ||s||/(1+||s||^2)*s; out = v; vsum += v.
// 4 threads per element (18 tiles each). t0: q = t0&3, g = t0>>2 = (b*NO+o)*16+e.
// Wave = 4 q x 16 e of one (b,o): combine q via xor(1,2), norm via xor(4..32).
// ---------------------------------------------------------------------------
__global__ __launch_bounds__(256)
void squash_kernel(const float* __restrict__ s_part,
                   float* __restrict__ vsum,
                   float* __restrict__ out,
                   const int accum) {
    const int t0 = blockIdx.x * 256 + threadIdx.x;   // < 4*40960
    const int q  = t0 & 3;
    const int g  = t0 >> 2;

    float s = 0.f;
    const float* sp = s_part + (size_t)(q * 18) * (B * NO * DE) + g;
#pragma unroll 9
    for (int i = 0; i < 18; ++i)
        s += sp[(size_t)i * (B * NO * DE)];
    s += __shfl_xor(s, 1);
    s += __shfl_xor(s, 2);        // full tile sum, all q lanes

    float nsq = s * s;
#pragma unroll
    for (int msk = 4; msk <= 32; msk <<= 1) nsq += __shfl_xor(nsq, msk);
    const float nrm   = sqrtf(nsq);
    const float scale = nrm / (1.f + nsq);
    const float val   = s * scale;

    if (q == 0) {
        out[g]  = val;                               // (B,NO,DE)
        vsum[g] = accum ? (vsum[g] + val) : val;
    }
}

extern "C" void kernel_launch(void* const* d_in, const int* in_sizes, int n_in,
                              void* d_out, int out_size, void* d_ws, size_t ws_size,
                              hipStream_t stream) {
    const float* u    = (const float*)d_in[0];
    const float* w    = (const float*)d_in[1];   // (N,NO,DI,DE)
    const float* bias = (const float*)d_in[2];   // (N,NO)
    // d_in[3] = r, static 3

    float* wsf    = (float*)d_ws;
    float* s_part = wsf + SP_OFF;
    float* vsum   = wsf + VS_OFF;
    float* out    = (float*)d_out;

    for (int it = 0; it < 3; ++it) {
        routing_kernel<<<dim3(NTILES, BGS), THREADS, 0, stream>>>(
            u, w, bias, vsum, s_part, it > 0);
        squash_kernel<<<(4 * B * NO * DE) / 256, 256, 0, stream>>>(
            s_part, vsum, out, it > 0);
    }
}

// Round 10
// 212.724 us; speedup vs baseline: 2.0096x; 2.0096x over previous
//
#include <hip/hip_runtime.h>

// Capsule dynamic routing — R7 structure (b-on-lanes / o-on-waves, wave-uniform
// scalar weight loads) + LDS-staged u + 1-barrier softmax + float4 squash.
// u_i:(B,N,DI) f32, w:(1,N,NO,DI,DE) f32, bias:(N,NO,1) f32, r=3.
// Identity: logits_r = u_ji . vsum (vsum = running sum of v; u_ji includes
// bias so the bias term folds in automatically).
// Routing block = 5 waves x 64 lanes; wave wv owns o in {2wv,2wv+1}; lane = b.
// Weight addrs wave-uniform -> compiler emits s_load (R7: SGPR=112) ->
// weights ride the scalar cache, not VMEM. u tile staged to LDS [k][b]
// (conflict-free ds_read_b32) -> in-loop VMEM = 0. Softmax via double-buffered
// 2x10x64 LDS exchange -> ONE barrier per n.

#define B    256
#define N    1152
#define NO   10
#define DI   8
#define DE   16
#define NTILE   8
#define NTILES  144    // N / NTILE
#define BG      64     // b per block (= lanes per wave)
#define BGS     4      // B / BG
#define THREADS 320    // 5 waves
#define KT      (NTILE * DI)   // 64 k-slots per tile

// ws layout (floats) — 23.76 MB (proven size)
#define SP_OFF 0
#define SP_SZ  (NTILES * B * NO * DE)   // 5,898,240
#define VS_OFF (SP_OFF + SP_SZ)
#define VS_SZ  (B * NO * DE)            // 40,960

// ---------------------------------------------------------------------------
// Routing pass. Grid: (144 n-tiles, 4 b-groups) x 320 threads.
// ---------------------------------------------------------------------------
__global__ __launch_bounds__(THREADS, 3)
void routing_kernel(const float* __restrict__ u,
                    const float* __restrict__ w,
                    const float* __restrict__ bias,
                    const float* __restrict__ vsum,
                    float* __restrict__ s_part,
                    const int has_v) {
    __shared__ float lds_u[KT * BG];        // 16 KB, layout [k][b]
    __shared__ float lgx[2][NO][BG];        // 5 KB double-buffered logit xchg
    const int tid  = threadIdx.x;
    const int lane = tid & 63;
    const int wv   = __builtin_amdgcn_readfirstlane(tid >> 6);  // 0..4 uniform
    const int o0   = wv * 2;
    const int b0   = blockIdx.y * BG;
    const int b    = b0 + lane;
    const int n0   = blockIdx.x * NTILE;

    // --- stage u tile: rows b0..b0+63, cols n0*8..+63, into [k][b] ---
    // src float4 idx: (b0+r)*2304 + n0*2 + c4  (u row = 9216 floats)
    for (int i = tid; i < BG * (KT / 4); i += THREADS) {   // 1024 float4
        const int r  = i >> 4;          // b row 0..63
        const int c4 = i & 15;          // col quad 0..15
        const float4 v4 = *((const float4*)u + (size_t)(b0 + r) * (N * DI / 4)
                            + n0 * (DI / 4) + c4);
        const int k = c4 * 4;
        lds_u[(k + 0) * BG + r] = v4.x;  // bank = r%32 per lane -> 2-way, free
        lds_u[(k + 1) * BG + r] = v4.y;
        lds_u[(k + 2) * BG + r] = v4.z;
        lds_u[(k + 3) * BG + r] = v4.w;
    }

    // vsum fragment for this thread's (b, o0..o0+1), full e — loop-invariant
    float4 vv[2][4];
#pragma unroll
    for (int oi = 0; oi < 2; ++oi)
#pragma unroll
        for (int eq = 0; eq < 4; ++eq)
            vv[oi][eq] = make_float4(0.f, 0.f, 0.f, 0.f);
    if (has_v) {
#pragma unroll
        for (int oi = 0; oi < 2; ++oi)
#pragma unroll
            for (int eq = 0; eq < 4; ++eq)
                vv[oi][eq] = *(const float4*)(vsum + ((size_t)b * NO + o0 + oi) * DE + eq * 4);
    }

    float4 acc[2][4];
#pragma unroll
    for (int oi = 0; oi < 2; ++oi)
#pragma unroll
        for (int eq = 0; eq < 4; ++eq)
            acc[oi][eq] = make_float4(0.f, 0.f, 0.f, 0.f);

    __syncthreads();   // u tile staged

    for (int i = 0; i < NTILE; ++i) {
        const int n = n0 + i;

        // u row from LDS: 8 conflict-free ds_read_b32 (lanes contiguous in b)
        float ur[DI];
#pragma unroll
        for (int d = 0; d < DI; ++d) ur[d] = lds_u[(i * DI + d) * BG + lane];

        // u_ji for (o0, o0+1), all 16 e — weight addrs wave-uniform (s_load)
        const float* wp = w + ((size_t)n * NO + o0) * (DI * DE);
        float4 uji[2][4];
#pragma unroll
        for (int oi = 0; oi < 2; ++oi) {
            const float bv = bias[n * NO + o0 + oi];
#pragma unroll
            for (int eq = 0; eq < 4; ++eq)
                uji[oi][eq] = make_float4(bv, bv, bv, bv);
#pragma unroll
            for (int d = 0; d < DI; ++d) {
                const float* wrow = wp + oi * (DI * DE) + d * DE;
#pragma unroll
                for (int eq = 0; eq < 4; ++eq) {
                    const float4 w4 = *(const float4*)(wrow + eq * 4);
                    uji[oi][eq].x += ur[d] * w4.x;
                    uji[oi][eq].y += ur[d] * w4.y;
                    uji[oi][eq].z += ur[d] * w4.z;
                    uji[oi][eq].w += ur[d] * w4.w;
                }
            }
        }

        float c[2];
        if (has_v) {
            // logits: full-e dot in-thread; exchange via double-buffered LDS
            const int buf = i & 1;
#pragma unroll
            for (int oi = 0; oi < 2; ++oi) {
                float lg = 0.f;
#pragma unroll
                for (int eq = 0; eq < 4; ++eq)
                    lg += uji[oi][eq].x * vv[oi][eq].x + uji[oi][eq].y * vv[oi][eq].y
                        + uji[oi][eq].z * vv[oi][eq].z + uji[oi][eq].w * vv[oi][eq].w;
                lgx[buf][o0 + oi][lane] = lg;
            }
            __syncthreads();   // single barrier: buffer parity protects reads
            float l[NO];
#pragma unroll
            for (int o = 0; o < NO; ++o) l[o] = lgx[buf][o][lane];

            float m = l[0];
#pragma unroll
            for (int o = 1; o < NO; ++o) m = fmaxf(m, l[o]);
            float sum = 0.f;
#pragma unroll
            for (int o = 0; o < NO; ++o) { l[o] = __expf(l[o] - m); sum += l[o]; }
            const float inv = 1.f / sum;
            c[0] = l[o0] * inv;
            c[1] = l[o0 + 1] * inv;
        } else {
            c[0] = 0.1f; c[1] = 0.1f;   // softmax of zeros
        }

#pragma unroll
        for (int oi = 0; oi < 2; ++oi)
#pragma unroll
            for (int eq = 0; eq < 4; ++eq) {
                acc[oi][eq].x += c[oi] * uji[oi][eq].x;
                acc[oi][eq].y += c[oi] * uji[oi][eq].y;
                acc[oi][eq].z += c[oi] * uji[oi][eq].z;
                acc[oi][eq].w += c[oi] * uji[oi][eq].w;
            }
    }

    // s_part[tile][b][o][e]
    float* sp = s_part + (((size_t)blockIdx.x * B + b) * NO + o0) * DE;
#pragma unroll
    for (int oi = 0; oi < 2; ++oi)
#pragma unroll
        for (int eq = 0; eq < 4; ++eq)
            *(float4*)(sp + oi * DE + eq * 4) = acc[oi][eq];
}

// ---------------------------------------------------------------------------
// Squash: s = sum_tiles s_part; v = ||s||/(1+||s||^2)*s; out = v; vsum += v.
// float4 per thread, 16-way tile split (9 tiles each). t0 < 163840:
// q = t0&15 (tile 16th), f4 = t0>>4 (0..10239) = (b*NO+o)*4 + eq.
// Wave = 16 q x 4 eq of ONE (b,o): combine q via xor(1,2,4,8) (per component),
// norm over eq via xor(16,32). Grid 640 blocks.
// ---------------------------------------------------------------------------
__global__ __launch_bounds__(256)
void squash_kernel(const float* __restrict__ s_part,
                   float* __restrict__ vsum,
                   float* __restrict__ out,
                   const int accum) {
    const int t0 = blockIdx.x * 256 + threadIdx.x;   // < 16*10240
    const int q  = t0 & 15;
    const int f4 = t0 >> 4;

    const float4* sp = (const float4*)s_part + (size_t)(q * 9) * (B * NO * DE / 4) + f4;
    float4 s = make_float4(0.f, 0.f, 0.f, 0.f);
#pragma unroll
    for (int i = 0; i < 9; ++i) {
        const float4 t = sp[(size_t)i * (B * NO * DE / 4)];
        s.x += t.x; s.y += t.y; s.z += t.z; s.w += t.w;
    }
#pragma unroll
    for (int msk = 1; msk <= 8; msk <<= 1) {
        s.x += __shfl_xor(s.x, msk);
        s.y += __shfl_xor(s.y, msk);
        s.z += __shfl_xor(s.z, msk);
        s.w += __shfl_xor(s.w, msk);
    }
    float nsq = s.x * s.x + s.y * s.y + s.z * s.z + s.w * s.w;
    nsq += __shfl_xor(nsq, 16);
    nsq += __shfl_xor(nsq, 32);     // full ||s||^2 over 16 e
    const float nrm   = sqrtf(nsq);
    const float scale = nrm / (1.f + nsq);

    if (q == 0) {
        const float4 val = make_float4(s.x * scale, s.y * scale, s.z * scale, s.w * scale);
        ((float4*)out)[f4] = val;
        float4* vp = (float4*)vsum + f4;
        if (accum) {
            const float4 old = *vp;
            *vp = make_float4(old.x + val.x, old.y + val.y, old.z + val.z, old.w + val.w);
        } else {
            *vp = val;
        }
    }
}

extern "C" void kernel_launch(void* const* d_in, const int* in_sizes, int n_in,
                              void* d_out, int out_size, void* d_ws, size_t ws_size,
                              hipStream_t stream) {
    const float* u    = (const float*)d_in[0];
    const float* w    = (const float*)d_in[1];   // (N,NO,DI,DE)
    const float* bias = (const float*)d_in[2];   // (N,NO)
    // d_in[3] = r, static 3

    float* wsf    = (float*)d_ws;
    float* s_part = wsf + SP_OFF;
    float* vsum   = wsf + VS_OFF;
    float* out    = (float*)d_out;

    for (int it = 0; it < 3; ++it) {
        routing_kernel<<<dim3(NTILES, BGS), THREADS, 0, stream>>>(
            u, w, bias, vsum, s_part, it > 0);
        squash_kernel<<<(16 * B * NO * DE / 4) / 256, 256, 0, stream>>>(
            s_part, vsum, out, it > 0);
    }
}